// Round 3
// baseline (757.101 us; speedup 1.0000x reference)
//
#include <hip/hip_runtime.h>

#define N_ 4
#define H_ 128
#define W_ 128
#define C_ 256
#define P2_ 64
#define CELLS_ 16
#define HEADS_ 8
#define TOPK_ 4
#define SCALE_ 0.0625f
#define TOK_ (N_*H_*W_)   // 65536

typedef short short8 __attribute__((ext_vector_type(8)));
typedef float f32x4  __attribute__((ext_vector_type(4)));

// fp32 -> bf16 hi (truncate, exact) + lo (RNE of residual)
__device__ __forceinline__ void split1(float f, ushort& h, ushort& l) {
    unsigned u = __float_as_uint(f);
    h = (ushort)(u >> 16);
    float hif = __uint_as_float(u & 0xFFFF0000u);
    unsigned ul = __float_as_uint(f - hif);
    ul = ul + 0x7FFFu + ((ul >> 16) & 1u);
    l = (ushort)(ul >> 16);
}

// ---------------- pooling: xpool (4x4 cells) + window means ----------------
__global__ __launch_bounds__(256) void pool_kernel(
    const float* __restrict__ x1, const float* __restrict__ x2,
    float* __restrict__ xpool, float* __restrict__ xwm)
{
    int c = threadIdx.x;
    int blk = blockIdx.x;            // [0, 2*N*P2)
    int b   = blk >> 8;
    int rem = blk & 255;
    int n   = rem >> 6;
    int win = rem & 63;
    int wh = win >> 3, ww = win & 7;
    const float* x = (b ? x2 : x1);
    size_t nbase = (size_t)n * H_ * W_ * C_;
    size_t prow = (size_t)(b*N_ + n)*P2_ + win;
    float wsum = 0.f;
    #pragma unroll
    for (int cell = 0; cell < 16; ++cell) {
        int a = cell >> 2, d = cell & 3;
        int h0 = wh*16 + a*4, w0 = ww*16 + d*4;
        float s = 0.f;
        #pragma unroll
        for (int dy = 0; dy < 4; ++dy)
            #pragma unroll
            for (int dx = 0; dx < 4; ++dx)
                s += x[nbase + ((size_t)(h0+dy)*W_ + (w0+dx))*C_ + c];
        xpool[(prow*CELLS_ + cell)*C_ + c] = s * (1.f/16.f);
        wsum += s;
    }
    xwm[prow*C_ + c] = wsum * (1.f/256.f);
}

// ---------------- W pre-split: fp32 -> bf16 hi (truncate) + lo (RNE) --------
__global__ __launch_bounds__(256) void wsplit_kernel(
    const float* __restrict__ Wqkv, const float* __restrict__ Wo,
    ushort* __restrict__ Wh, ushort* __restrict__ Wl)
{
    int e = (blockIdx.x*256 + threadIdx.x) * 4;
    const float* src = (e < 768*256) ? (Wqkv + e) : (Wo + (e - 768*256));
    float4 f = *(const float4*)src;
    float fv[4] = {f.x, f.y, f.z, f.w};
    ushort hu[4], lu[4];
    #pragma unroll
    for (int j = 0; j < 4; ++j) split1(fv[j], hu[j], lu[j]);
    *(uint2*)&Wh[e] = *(uint2*)hu;
    *(uint2*)&Wl[e] = *(uint2*)lu;
}

// ---------------- MFMA GEMM v2: 128-row tile, pair-batched dispatches -------
// blockIdx.y selects an independent gemm slice {A, w_base, bias, out, stride}.
// Block: 128 rows x 256 cols, 4 waves, wave-tile 128x64 (acc 8x4 of 16x16).
// A fp32 split on the fly; W pre-split (Wh/Wl). In-place safe for out==A:
// block reads only its own 128 rows, writes them only in the epilogue.
#define AST 40   // LDS row stride (ushorts) = 80 B -> <=2-way bank alias
__global__ __launch_bounds__(256,2) void gemm_mfma(
    const float* __restrict__ A0, const float* __restrict__ A1,
    const ushort* __restrict__ Wh, const ushort* __restrict__ Wl,
    int wb0, int wb1,
    const float* __restrict__ b0, const float* __restrict__ b1,
    float* __restrict__ o0, float* __restrict__ o1, int os0, int os1)
{
    __shared__ ushort Ah[128*AST], Al[128*AST];   // 10240 B each
    __shared__ ushort Bh[256*AST], Bl[256*AST];   // 20480 B each
    int y = blockIdx.y;
    const float* A    = y ? A1 : A0;
    int w_base        = y ? wb1 : wb0;
    const float* bias = y ? b1 : b0;
    float* out        = y ? o1 : o0;
    int ostride       = y ? os1 : os0;

    int tid = threadIdx.x;
    int row0 = blockIdx.x * 128;
    int wv = tid >> 6, lane = tid & 63;
    int quad = lane >> 4, l15 = lane & 15;

    f32x4 acc[8][4];
    #pragma unroll
    for (int mt = 0; mt < 8; ++mt)
        #pragma unroll
        for (int nt = 0; nt < 4; ++nt)
            acc[mt][nt] = f32x4{0.f, 0.f, 0.f, 0.f};

    int srow = tid >> 1;            // 0..127
    int skk  = (tid & 1) * 16;      // 0,16
    const float*  aptr = A  + (size_t)(row0 + srow)*256 + skk;
    const ushort* whp  = Wh + (size_t)(w_base + tid)*256;
    const ushort* wlp  = Wl + (size_t)(w_base + tid)*256;

    for (int ck = 0; ck < 256; ck += 32) {
        // ---- stage A chunk (128x32 fp32 -> split bf16), 16 elems/thread ----
        float4 f0 = *(const float4*)(aptr + ck);
        float4 f1 = *(const float4*)(aptr + ck + 4);
        float4 f2 = *(const float4*)(aptr + ck + 8);
        float4 f3 = *(const float4*)(aptr + ck + 12);
        float fv[16] = {f0.x,f0.y,f0.z,f0.w, f1.x,f1.y,f1.z,f1.w,
                        f2.x,f2.y,f2.z,f2.w, f3.x,f3.y,f3.z,f3.w};
        ushort hu[16], lu[16];
        #pragma unroll
        for (int j = 0; j < 16; ++j) split1(fv[j], hu[j], lu[j]);
        *(uint4*)&Ah[srow*AST + skk]     = *(uint4*)&hu[0];
        *(uint4*)&Ah[srow*AST + skk + 8] = *(uint4*)&hu[8];
        *(uint4*)&Al[srow*AST + skk]     = *(uint4*)&lu[0];
        *(uint4*)&Al[srow*AST + skk + 8] = *(uint4*)&lu[8];
        // ---- stage B chunk (256x32 bf16 copy), row tid, 32 cols ----
        #pragma unroll
        for (int p = 0; p < 4; ++p) {
            *(uint4*)&Bh[tid*AST + p*8] = *(const uint4*)(whp + ck + p*8);
            *(uint4*)&Bl[tid*AST + p*8] = *(const uint4*)(wlp + ck + p*8);
        }
        __syncthreads();
        // ---- compute: wave-tile 128x64 = 8x4 of 16x16, 3 MFMAs each ----
        short8 bh[4], bl[4];
        #pragma unroll
        for (int nt = 0; nt < 4; ++nt) {
            int r = wv*64 + nt*16 + l15;
            bh[nt] = *(const short8*)&Bh[r*AST + quad*8];
            bl[nt] = *(const short8*)&Bl[r*AST + quad*8];
        }
        #pragma unroll
        for (int mt = 0; mt < 8; ++mt) {
            int r = mt*16 + l15;
            short8 ah = *(const short8*)&Ah[r*AST + quad*8];
            short8 al = *(const short8*)&Al[r*AST + quad*8];
            #pragma unroll
            for (int nt = 0; nt < 4; ++nt) {
                acc[mt][nt] = __builtin_amdgcn_mfma_f32_16x16x32_bf16(ah, bh[nt], acc[mt][nt], 0, 0, 0);
                acc[mt][nt] = __builtin_amdgcn_mfma_f32_16x16x32_bf16(ah, bl[nt], acc[mt][nt], 0, 0, 0);
                acc[mt][nt] = __builtin_amdgcn_mfma_f32_16x16x32_bf16(al, bh[nt], acc[mt][nt], 0, 0, 0);
            }
        }
        __syncthreads();
    }
    // ---- epilogue: C/D layout col=lane&15, row=quad*4+reg ----
    float bv[4];
    #pragma unroll
    for (int nt = 0; nt < 4; ++nt) bv[nt] = bias[wv*64 + nt*16 + l15];
    #pragma unroll
    for (int mt = 0; mt < 8; ++mt) {
        int rg = row0 + mt*16 + quad*4;
        #pragma unroll
        for (int r = 0; r < 4; ++r) {
            float* orow = out + (size_t)(rg + r)*ostride + wv*64 + l15;
            #pragma unroll
            for (int nt = 0; nt < 4; ++nt)
                orow[nt*16] = acc[mt][nt][r] + bv[nt];
        }
    }
}

// ---------------- routing: logits + diag=1.0 + top-4 (tie -> lower index) ----
__global__ __launch_bounds__(64) void route_kernel(
    const float* __restrict__ qwin, const float* __restrict__ kwin,
    int* __restrict__ idx)
{
    int tid = threadIdx.x;            // 64 = one wave
    int blk = blockIdx.x;             // [0, 2*N*64)
    int pair = blk >> 8;
    int rem = blk & 255;
    int n = rem >> 6, i = rem & 63;
    int qb = (pair == 0) ? 1 : 0;     // idx1 = route(q2w, k1w)
    int kb = (pair == 0) ? 0 : 1;
    const float* q = qwin + ((size_t)(qb*N_+n)*64 + i)*256;
    const float* k = kwin + ((size_t)(kb*N_+n)*64 + tid)*256;
    float s = 0.f;
    for (int c = 0; c < 256; ++c) s += q[c]*k[c];
    s *= SCALE_;
    if (tid == i) s = 1.0f;
    int* orow = idx + ((size_t)pair*N_*64 + rem)*4;
    for (int t = 0; t < 4; ++t) {
        float v = s; int bi = tid;
        #pragma unroll
        for (int off = 32; off > 0; off >>= 1) {
            float ov = __shfl_down(v, off);
            int   oi = __shfl_down(bi, off);
            if (ov > v || (ov == v && oi < bi)) { v = ov; bi = oi; }
        }
        bi = __shfl(bi, 0);
        if (tid == 0) orow[t] = bi;
        if (tid == bi) s = -3.0e38f;
    }
}

// ---------------- LePE: depthwise 3x3 'SAME' conv over v image + bias --------
__global__ __launch_bounds__(256) void lepe_kernel(
    const float* __restrict__ v, const float* __restrict__ lw,
    const float* __restrict__ lb, float* __restrict__ out)
{
    int c = threadIdx.x;
    int blk = blockIdx.x;           // N*H*(W/32) = 2048
    int wseg = blk & 3;
    int h = (blk >> 2) & 127;
    int n = blk >> 9;
    float wk[9];
    #pragma unroll
    for (int t = 0; t < 9; ++t) wk[t] = lw[c*9 + t];
    float bias = lb[c];
    for (int px = 0; px < 32; ++px) {
        int w = wseg*32 + px;
        float acc = bias;
        #pragma unroll
        for (int ky = 0; ky < 3; ++ky) {
            int hh = h + ky - 1;
            if (hh < 0 || hh >= 128) continue;
            #pragma unroll
            for (int kx = 0; kx < 3; ++kx) {
                int wp = w + kx - 1;
                if (wp < 0 || wp >= 128) continue;
                acc += wk[ky*3+kx] * v[(((size_t)n*128 + hh)*128 + wp)*256 + c];
            }
        }
        out[(((size_t)n*128 + h)*128 + w)*256 + c] = acc;
    }
}

// ---------------- attention v3: MFMA + LDS alias, one head per block ---------
#define KST 40   // K row stride (ushorts): 80B -> 2-way bank alias max
#define VST 72   // Vt / P row stride (ushorts): 144B -> 2-way
__global__ __launch_bounds__(256) void attn_kernel(
    const float* __restrict__ qbuf, const float* __restrict__ kvp,
    const int* __restrict__ idx, float* __restrict__ out)
{
    __shared__ __align__(16) char smem[19456];
    __shared__ int sel[4];
    ushort* Kh  = (ushort*)smem;
    ushort* Kl  = (ushort*)(smem + 5120);
    ushort* Vth = (ushort*)(smem + 10240);
    ushort* Vtl = (ushort*)(smem + 14848);

    int n    = blockIdx.x >> 6;
    int win  = blockIdx.x & 63;
    int head = blockIdx.y;
    int tid  = threadIdx.x;
    int wv = tid >> 6, lane = tid & 63;
    int quad = lane >> 4, l15 = lane & 15;
    int wh = win >> 3, ww = win & 7;
    if (tid < 4) sel[tid] = idx[((size_t)n*64 + win)*4 + tid];
    __syncthreads();
    const float* kvbase = kvp + (size_t)n*(64*16*512);

    // ---- stage K[64][32] hi/lo ----
    {
        int kkey = tid >> 2, kd = (tid & 3) * 8;
        const float* src = kvbase
            + (size_t)(sel[kkey>>4]*16 + (kkey&15))*512 + head*32 + kd;
        float4 f0 = *(const float4*)src;
        float4 f1 = *(const float4*)(src + 4);
        float fv[8] = {f0.x,f0.y,f0.z,f0.w, f1.x,f1.y,f1.z,f1.w};
        ushort hu[8], lu[8];
        #pragma unroll
        for (int j = 0; j < 8; ++j) split1(fv[j], hu[j], lu[j]);
        *(uint4*)&Kh[kkey*KST + kd] = *(uint4*)hu;
        *(uint4*)&Kl[kkey*KST + kd] = *(uint4*)lu;
    }
    // ---- stage Vt[32][64] hi/lo (transposed gather) ----
    {
        int vd = tid >> 3, vk = (tid & 7) * 8;
        int vcell = sel[vk >> 4]*16 + (vk & 15);
        float fv[8];
        #pragma unroll
        for (int j = 0; j < 8; ++j)
            fv[j] = kvbase[(size_t)(vcell + j)*512 + 256 + head*32 + vd];
        ushort hu[8], lu[8];
        #pragma unroll
        for (int j = 0; j < 8; ++j) split1(fv[j], hu[j], lu[j]);
        *(uint4*)&Vth[vd*VST + vk] = *(uint4*)hu;
        *(uint4*)&Vtl[vd*VST + vk] = *(uint4*)lu;
    }
    __syncthreads();
    // ---- hoist fragments: K (A-side), Vt (B-side) ----
    short8 kfh[4], kfl[4];
    #pragma unroll
    for (int kt = 0; kt < 4; ++kt) {
        kfh[kt] = *(const short8*)&Kh[(kt*16 + l15)*KST + quad*8];
        kfl[kt] = *(const short8*)&Kl[(kt*16 + l15)*KST + quad*8];
    }
    short8 vfh[2][2], vfl[2][2];   // [chunk c][d-tile nt]
    #pragma unroll
    for (int c = 0; c < 2; ++c)
        #pragma unroll
        for (int nt = 0; nt < 2; ++nt) {
            vfh[c][nt] = *(const short8*)&Vth[(nt*16 + l15)*VST + c*32 + quad*8];
            vfl[c][nt] = *(const short8*)&Vtl[(nt*16 + l15)*VST + c*32 + quad*8];
        }
    __syncthreads();   // staging LDS now dead -> safe to alias with P
    ushort* Ph = (ushort*)(smem + wv*4608);       // 16*VST us
    ushort* Pl = Ph + 1152;

    // ---- pixel tiles ----
    #pragma unroll
    for (int pt = 0; pt < 4; ++pt) {
        int ph = wv*4 + pt;
        const float* qp = qbuf
            + ((((size_t)n*128 + wh*16 + ph)*128 + ww*16 + l15)*256)
            + head*32 + quad*8;
        float4 q0 = *(const float4*)qp;
        float4 q1 = *(const float4*)(qp + 4);
        float qv[8] = {q0.x,q0.y,q0.z,q0.w, q1.x,q1.y,q1.z,q1.w};
        ushort qh_[8], ql_[8];
        #pragma unroll
        for (int j = 0; j < 8; ++j) split1(qv[j]*SCALE_, qh_[j], ql_[j]);
        short8 qh = *(short8*)qh_, ql = *(short8*)ql_;
        f32x4 s[4];
        #pragma unroll
        for (int kt = 0; kt < 4; ++kt) s[kt] = f32x4{0.f,0.f,0.f,0.f};
        #pragma unroll
        for (int kt = 0; kt < 4; ++kt) {
            s[kt] = __builtin_amdgcn_mfma_f32_16x16x32_bf16(kfh[kt], qh, s[kt], 0, 0, 0);
            s[kt] = __builtin_amdgcn_mfma_f32_16x16x32_bf16(kfh[kt], ql, s[kt], 0, 0, 0);
            s[kt] = __builtin_amdgcn_mfma_f32_16x16x32_bf16(kfl[kt], qh, s[kt], 0, 0, 0);
        }
        float m = -3.0e38f;
        #pragma unroll
        for (int kt = 0; kt < 4; ++kt)
            #pragma unroll
            for (int r = 0; r < 4; ++r) m = fmaxf(m, s[kt][r]);
        m = fmaxf(m, __shfl_xor(m, 16));
        m = fmaxf(m, __shfl_xor(m, 32));
        float p[16]; float lsum = 0.f;
        #pragma unroll
        for (int kt = 0; kt < 4; ++kt)
            #pragma unroll
            for (int r = 0; r < 4; ++r) {
                float pe = __expf(s[kt][r] - m);
                p[kt*4 + r] = pe;
                lsum += pe;
            }
        lsum += __shfl_xor(lsum, 16);
        lsum += __shfl_xor(lsum, 32);
        float inv = 1.f / lsum;
        #pragma unroll
        for (int kt = 0; kt < 4; ++kt) {
            ushort h4[4], l4[4];
            #pragma unroll
            for (int r = 0; r < 4; ++r) split1(p[kt*4 + r]*inv, h4[r], l4[r]);
            uint2 wph = { (uint)h4[0] | ((uint)h4[1] << 16),
                          (uint)h4[2] | ((uint)h4[3] << 16) };
            uint2 wpl = { (uint)l4[0] | ((uint)l4[1] << 16),
                          (uint)l4[2] | ((uint)l4[3] << 16) };
            *(uint2*)&Ph[l15*VST + kt*16 + quad*4] = wph;
            *(uint2*)&Pl[l15*VST + kt*16 + quad*4] = wpl;
        }
        short8 pfh[2], pfl[2];
        #pragma unroll
        for (int c = 0; c < 2; ++c) {
            pfh[c] = *(const short8*)&Ph[l15*VST + c*32 + quad*8];
            pfl[c] = *(const short8*)&Pl[l15*VST + c*32 + quad*8];
        }
        f32x4 o[2];
        o[0] = f32x4{0.f,0.f,0.f,0.f};
        o[1] = f32x4{0.f,0.f,0.f,0.f};
        #pragma unroll
        for (int c = 0; c < 2; ++c)
            #pragma unroll
            for (int nt = 0; nt < 2; ++nt) {
                o[nt] = __builtin_amdgcn_mfma_f32_16x16x32_bf16(pfh[c], vfh[c][nt], o[nt], 0, 0, 0);
                o[nt] = __builtin_amdgcn_mfma_f32_16x16x32_bf16(pfl[c], vfh[c][nt], o[nt], 0, 0, 0);
                o[nt] = __builtin_amdgcn_mfma_f32_16x16x32_bf16(pfh[c], vfl[c][nt], o[nt], 0, 0, 0);
            }
        #pragma unroll
        for (int r = 0; r < 4; ++r) {
            float* orow = out
                + ((((size_t)n*128 + wh*16 + ph)*128 + ww*16 + quad*4 + r)*256)
                + head*32 + l15;
            #pragma unroll
            for (int nt = 0; nt < 2; ++nt)
                orow[nt*16] += o[nt][r];
        }
    }
}

extern "C" void kernel_launch(void* const* d_in, const int* in_sizes, int n_in,
                              void* d_out, int out_size, void* d_ws, size_t ws_size,
                              hipStream_t stream)
{
    const float* x1   = (const float*)d_in[0];
    const float* x2   = (const float*)d_in[1];
    const float* Wqkv = (const float*)d_in[2];
    const float* bqkv = (const float*)d_in[3];
    const float* lw   = (const float*)d_in[4];
    const float* lb   = (const float*)d_in[5];
    const float* Wo   = (const float*)d_in[6];
    const float* bo   = (const float*)d_in[7];
    float* out1 = (float*)d_out;
    float* out2 = out1 + (size_t)TOK_*C_;

    float* ws    = (float*)d_ws;
    float* xpool = ws;                          //  2,097,152 f
    float* xwm   = xpool + 2097152;             //    131,072 f
    float* kvp   = xwm   + 131072;              //  4,194,304 f
    float* qwin  = kvp   + 4194304;             //    131,072 f
    float* kwin  = qwin  + 131072;              //    131,072 f
    int*   idx   = (int*)(kwin + 131072);       //      2,048 i
    ushort* Wh   = (ushort*)(idx + 2048);       //    262,144 us
    ushort* Wl   = Wh + 262144;                 //    262,144 us
    float* bufQ1 = (float*)(Wl + 262144);       // 16,777,216 f
    float* bufQ2 = bufQ1 + 16777216;            // 16,777,216 f
    float* bufV1 = bufQ2 + 16777216;            // 16,777,216 f
    float* bufV2 = bufV1 + 16777216;            // 16,777,216 f

    // 0) pre-split weights (Wqkv rows 0-767, Wo rows 768-1023)
    wsplit_kernel<<<dim3(256), dim3(256), 0, stream>>>(Wqkv, Wo, Wh, Wl);
    // 1) pooled image + window means (both branches)
    pool_kernel<<<dim3(512), dim3(256), 0, stream>>>(x1, x2, xpool, xwm);
    // 2) kv_pool: k (cols 0-255) and v (cols 256-511) of kvp, pair-batched
    gemm_mfma<<<dim3(64,2), dim3(256), 0, stream>>>(
        xpool, xpool, Wh, Wl, 256, 512, bqkv+256, bqkv+512,
        kvp, kvp+256, 512, 512);
    // 3) window-mean projections q/k, pair-batched (M=512)
    gemm_mfma<<<dim3(4,2), dim3(256), 0, stream>>>(
        xwm, xwm, Wh, Wl, 0, 256, bqkv, bqkv+256,
        qwin, kwin, 256, 256);
    // 4) routing (both pairs)
    route_kernel<<<dim3(512), dim3(64), 0, stream>>>(qwin, kwin, idx);
    // 5) batch A: q2 (from x2) + v1 (from x1)
    gemm_mfma<<<dim3(512,2), dim3(256), 0, stream>>>(
        x2, x1, Wh, Wl, 0, 512, bqkv, bqkv+512,
        bufQ2, bufV1, 256, 256);
    // 6) batch B: q1 (from x1) + v2 (from x2)
    gemm_mfma<<<dim3(512,2), dim3(256), 0, stream>>>(
        x1, x2, Wh, Wl, 0, 512, bqkv, bqkv+512,
        bufQ1, bufV2, 256, 256);
    // 7) lepe -> out1/out2
    lepe_kernel<<<dim3(2048), dim3(256), 0, stream>>>(bufV1, lw, lb, out1);
    lepe_kernel<<<dim3(2048), dim3(256), 0, stream>>>(bufV2, lw, lb, out2);
    // 8) attention: attend(q2, kv1, idx1) += out1 ; attend(q1, kv2, idx2) += out2
    attn_kernel<<<dim3(256,8), dim3(256), 0, stream>>>(bufQ2, kvp, idx, out1);
    attn_kernel<<<dim3(256,8), dim3(256), 0, stream>>>(bufQ1, kvp + 2097152, idx + N_*64*4, out2);
    // 9) final projection, pair-batched, in-place (blocks own rows exclusively)
    gemm_mfma<<<dim3(512,2), dim3(256), 0, stream>>>(
        out1, out2, Wh, Wl, 768, 768, bo, bo,
        out1, out2, 256, 256);
}

// Round 4
// 728.217 us; speedup vs baseline: 1.0397x; 1.0397x over previous
//
#include <hip/hip_runtime.h>

#define N_ 4
#define H_ 128
#define W_ 128
#define C_ 256
#define P2_ 64
#define CELLS_ 16
#define HEADS_ 8
#define TOPK_ 4
#define SCALE_ 0.0625f
#define TOK_ (N_*H_*W_)   // 65536

typedef short short8 __attribute__((ext_vector_type(8)));
typedef float f32x4  __attribute__((ext_vector_type(4)));

// fp32 -> bf16 hi (truncate, exact) + lo (RNE of residual)
__device__ __forceinline__ void split1(float f, ushort& h, ushort& l) {
    unsigned u = __float_as_uint(f);
    h = (ushort)(u >> 16);
    float hif = __uint_as_float(u & 0xFFFF0000u);
    unsigned ul = __float_as_uint(f - hif);
    ul = ul + 0x7FFFu + ((ul >> 16) & 1u);
    l = (ushort)(ul >> 16);
}

// ---------------- pooling: xpool (4x4 cells) + window means ----------------
__global__ __launch_bounds__(256) void pool_kernel(
    const float* __restrict__ x1, const float* __restrict__ x2,
    float* __restrict__ xpool, float* __restrict__ xwm)
{
    int c = threadIdx.x;
    int blk = blockIdx.x;            // [0, 2*N*P2)
    int b   = blk >> 8;
    int rem = blk & 255;
    int n   = rem >> 6;
    int win = rem & 63;
    int wh = win >> 3, ww = win & 7;
    const float* x = (b ? x2 : x1);
    size_t nbase = (size_t)n * H_ * W_ * C_;
    size_t prow = (size_t)(b*N_ + n)*P2_ + win;
    float wsum = 0.f;
    #pragma unroll
    for (int cell = 0; cell < 16; ++cell) {
        int a = cell >> 2, d = cell & 3;
        int h0 = wh*16 + a*4, w0 = ww*16 + d*4;
        float s = 0.f;
        #pragma unroll
        for (int dy = 0; dy < 4; ++dy)
            #pragma unroll
            for (int dx = 0; dx < 4; ++dx)
                s += x[nbase + ((size_t)(h0+dy)*W_ + (w0+dx))*C_ + c];
        xpool[(prow*CELLS_ + cell)*C_ + c] = s * (1.f/16.f);
        wsum += s;
    }
    xwm[prow*C_ + c] = wsum * (1.f/256.f);
}

// ---------------- W pre-split: fp32 -> bf16 hi (truncate) + lo (RNE) --------
__global__ __launch_bounds__(256) void wsplit_kernel(
    const float* __restrict__ Wqkv, const float* __restrict__ Wo,
    ushort* __restrict__ Wh, ushort* __restrict__ Wl)
{
    int e = (blockIdx.x*256 + threadIdx.x) * 4;
    const float* src = (e < 768*256) ? (Wqkv + e) : (Wo + (e - 768*256));
    float4 f = *(const float4*)src;
    float fv[4] = {f.x, f.y, f.z, f.w};
    ushort hu[4], lu[4];
    #pragma unroll
    for (int j = 0; j < 4; ++j) split1(fv[j], hu[j], lu[j]);
    *(uint2*)&Wh[e] = *(uint2*)hu;
    *(uint2*)&Wl[e] = *(uint2*)lu;
}

// ---------------- MFMA GEMM v3: 128-row tile, B-frags direct from global ----
// blockIdx.y selects an independent gemm slice {A, w_base, bias, out, stride}.
// Block: 128 rows x 256 cols, 4 waves, wave-tile 128x64 (acc 8x4 of 16x16).
// A fp32 split on the fly through LDS (shared across waves); B (pre-split W)
// read directly global->register in frag layout: W is L2-resident, so this
// removes 16 of 36 b128 LDS ops per thread per K-step (LDS was the bound).
// In-place safe for out==A: block reads only its own 128 rows.
#define AST 40   // LDS row stride (ushorts) = 80 B -> <=2-way bank alias
__global__ __launch_bounds__(256,2) void gemm_mfma(
    const float* __restrict__ A0, const float* __restrict__ A1,
    const ushort* __restrict__ Wh, const ushort* __restrict__ Wl,
    int wb0, int wb1,
    const float* __restrict__ b0, const float* __restrict__ b1,
    float* __restrict__ o0, float* __restrict__ o1, int os0, int os1)
{
    __shared__ ushort Ah[128*AST], Al[128*AST];   // 10240 B each
    int y = blockIdx.y;
    const float* A    = y ? A1 : A0;
    int w_base        = y ? wb1 : wb0;
    const float* bias = y ? b1 : b0;
    float* out        = y ? o1 : o0;
    int ostride       = y ? os1 : os0;

    int tid = threadIdx.x;
    int row0 = blockIdx.x * 128;
    int wv = tid >> 6, lane = tid & 63;
    int quad = lane >> 4, l15 = lane & 15;

    f32x4 acc[8][4];
    #pragma unroll
    for (int mt = 0; mt < 8; ++mt)
        #pragma unroll
        for (int nt = 0; nt < 4; ++nt)
            acc[mt][nt] = f32x4{0.f, 0.f, 0.f, 0.f};

    int srow = tid >> 1;            // 0..127
    int skk  = (tid & 1) * 16;      // 0,16
    const float*  aptr = A  + (size_t)(row0 + srow)*256 + skk;
    // per-lane B-frag base: W row (w_base + wv*64 + l15), cols quad*8..
    const ushort* wfh = Wh + (size_t)(w_base + wv*64 + l15)*256 + quad*8;
    const ushort* wfl = Wl + (size_t)(w_base + wv*64 + l15)*256 + quad*8;

    for (int ck = 0; ck < 256; ck += 32) {
        // ---- B-frags: direct global (L2-hot), issued before the barrier ----
        short8 bh[4], bl[4];
        #pragma unroll
        for (int nt = 0; nt < 4; ++nt) {
            bh[nt] = *(const short8*)(wfh + (size_t)nt*16*256 + ck);
            bl[nt] = *(const short8*)(wfl + (size_t)nt*16*256 + ck);
        }
        // ---- stage A chunk (128x32 fp32 -> split bf16), 16 elems/thread ----
        float4 f0 = *(const float4*)(aptr + ck);
        float4 f1 = *(const float4*)(aptr + ck + 4);
        float4 f2 = *(const float4*)(aptr + ck + 8);
        float4 f3 = *(const float4*)(aptr + ck + 12);
        float fv[16] = {f0.x,f0.y,f0.z,f0.w, f1.x,f1.y,f1.z,f1.w,
                        f2.x,f2.y,f2.z,f2.w, f3.x,f3.y,f3.z,f3.w};
        ushort hu[16], lu[16];
        #pragma unroll
        for (int j = 0; j < 16; ++j) split1(fv[j], hu[j], lu[j]);
        *(uint4*)&Ah[srow*AST + skk]     = *(uint4*)&hu[0];
        *(uint4*)&Ah[srow*AST + skk + 8] = *(uint4*)&hu[8];
        *(uint4*)&Al[srow*AST + skk]     = *(uint4*)&lu[0];
        *(uint4*)&Al[srow*AST + skk + 8] = *(uint4*)&lu[8];
        __syncthreads();
        // ---- compute: wave-tile 128x64 = 8x4 of 16x16, 3 MFMAs each ----
        #pragma unroll
        for (int mt = 0; mt < 8; ++mt) {
            int r = mt*16 + l15;
            short8 ah = *(const short8*)&Ah[r*AST + quad*8];
            short8 al = *(const short8*)&Al[r*AST + quad*8];
            #pragma unroll
            for (int nt = 0; nt < 4; ++nt) {
                acc[mt][nt] = __builtin_amdgcn_mfma_f32_16x16x32_bf16(ah, bh[nt], acc[mt][nt], 0, 0, 0);
                acc[mt][nt] = __builtin_amdgcn_mfma_f32_16x16x32_bf16(ah, bl[nt], acc[mt][nt], 0, 0, 0);
                acc[mt][nt] = __builtin_amdgcn_mfma_f32_16x16x32_bf16(al, bh[nt], acc[mt][nt], 0, 0, 0);
            }
        }
        __syncthreads();
    }
    // ---- epilogue: C/D layout col=lane&15, row=quad*4+reg ----
    float bv[4];
    #pragma unroll
    for (int nt = 0; nt < 4; ++nt) bv[nt] = bias[wv*64 + nt*16 + l15];
    #pragma unroll
    for (int mt = 0; mt < 8; ++mt) {
        int rg = row0 + mt*16 + quad*4;
        #pragma unroll
        for (int r = 0; r < 4; ++r) {
            float* orow = out + (size_t)(rg + r)*ostride + wv*64 + l15;
            #pragma unroll
            for (int nt = 0; nt < 4; ++nt)
                orow[nt*16] = acc[mt][nt][r] + bv[nt];
        }
    }
}

// ---------------- routing: logits + diag=1.0 + top-4 (tie -> lower index) ----
__global__ __launch_bounds__(64) void route_kernel(
    const float* __restrict__ qwin, const float* __restrict__ kwin,
    int* __restrict__ idx)
{
    int tid = threadIdx.x;            // 64 = one wave
    int blk = blockIdx.x;             // [0, 2*N*64)
    int pair = blk >> 8;
    int rem = blk & 255;
    int n = rem >> 6, i = rem & 63;
    int qb = (pair == 0) ? 1 : 0;     // idx1 = route(q2w, k1w)
    int kb = (pair == 0) ? 0 : 1;
    const float* q = qwin + ((size_t)(qb*N_+n)*64 + i)*256;
    const float* k = kwin + ((size_t)(kb*N_+n)*64 + tid)*256;
    float s = 0.f;
    for (int c = 0; c < 256; ++c) s += q[c]*k[c];
    s *= SCALE_;
    if (tid == i) s = 1.0f;
    int* orow = idx + ((size_t)pair*N_*64 + rem)*4;
    for (int t = 0; t < 4; ++t) {
        float v = s; int bi = tid;
        #pragma unroll
        for (int off = 32; off > 0; off >>= 1) {
            float ov = __shfl_down(v, off);
            int   oi = __shfl_down(bi, off);
            if (ov > v || (ov == v && oi < bi)) { v = ov; bi = oi; }
        }
        bi = __shfl(bi, 0);
        if (tid == 0) orow[t] = bi;
        if (tid == bi) s = -3.0e38f;
    }
}

// ---------------- LePE: depthwise 3x3 'SAME' conv over v image + bias --------
__global__ __launch_bounds__(256) void lepe_kernel(
    const float* __restrict__ v, const float* __restrict__ lw,
    const float* __restrict__ lb, float* __restrict__ out)
{
    int c = threadIdx.x;
    int blk = blockIdx.x;           // N*H*(W/32) = 2048
    int wseg = blk & 3;
    int h = (blk >> 2) & 127;
    int n = blk >> 9;
    float wk[9];
    #pragma unroll
    for (int t = 0; t < 9; ++t) wk[t] = lw[c*9 + t];
    float bias = lb[c];
    for (int px = 0; px < 32; ++px) {
        int w = wseg*32 + px;
        float acc = bias;
        #pragma unroll
        for (int ky = 0; ky < 3; ++ky) {
            int hh = h + ky - 1;
            if (hh < 0 || hh >= 128) continue;
            #pragma unroll
            for (int kx = 0; kx < 3; ++kx) {
                int wp = w + kx - 1;
                if (wp < 0 || wp >= 128) continue;
                acc += wk[ky*3+kx] * v[(((size_t)n*128 + hh)*128 + wp)*256 + c];
            }
        }
        out[(((size_t)n*128 + h)*128 + w)*256 + c] = acc;
    }
}

// ---------------- attention v3: MFMA + LDS alias, one head per block ---------
#define KST 40   // K row stride (ushorts): 80B -> 2-way bank alias max
#define VST 72   // Vt / P row stride (ushorts): 144B -> 2-way
__global__ __launch_bounds__(256) void attn_kernel(
    const float* __restrict__ qbuf, const float* __restrict__ kvp,
    const int* __restrict__ idx, float* __restrict__ out)
{
    __shared__ __align__(16) char smem[19456];
    __shared__ int sel[4];
    ushort* Kh  = (ushort*)smem;
    ushort* Kl  = (ushort*)(smem + 5120);
    ushort* Vth = (ushort*)(smem + 10240);
    ushort* Vtl = (ushort*)(smem + 14848);

    int n    = blockIdx.x >> 6;
    int win  = blockIdx.x & 63;
    int head = blockIdx.y;
    int tid  = threadIdx.x;
    int wv = tid >> 6, lane = tid & 63;
    int quad = lane >> 4, l15 = lane & 15;
    int wh = win >> 3, ww = win & 7;
    if (tid < 4) sel[tid] = idx[((size_t)n*64 + win)*4 + tid];
    __syncthreads();
    const float* kvbase = kvp + (size_t)n*(64*16*512);

    // ---- stage K[64][32] hi/lo ----
    {
        int kkey = tid >> 2, kd = (tid & 3) * 8;
        const float* src = kvbase
            + (size_t)(sel[kkey>>4]*16 + (kkey&15))*512 + head*32 + kd;
        float4 f0 = *(const float4*)src;
        float4 f1 = *(const float4*)(src + 4);
        float fv[8] = {f0.x,f0.y,f0.z,f0.w, f1.x,f1.y,f1.z,f1.w};
        ushort hu[8], lu[8];
        #pragma unroll
        for (int j = 0; j < 8; ++j) split1(fv[j], hu[j], lu[j]);
        *(uint4*)&Kh[kkey*KST + kd] = *(uint4*)hu;
        *(uint4*)&Kl[kkey*KST + kd] = *(uint4*)lu;
    }
    // ---- stage Vt[32][64] hi/lo (transposed gather) ----
    {
        int vd = tid >> 3, vk = (tid & 7) * 8;
        int vcell = sel[vk >> 4]*16 + (vk & 15);
        float fv[8];
        #pragma unroll
        for (int j = 0; j < 8; ++j)
            fv[j] = kvbase[(size_t)(vcell + j)*512 + 256 + head*32 + vd];
        ushort hu[8], lu[8];
        #pragma unroll
        for (int j = 0; j < 8; ++j) split1(fv[j], hu[j], lu[j]);
        *(uint4*)&Vth[vd*VST + vk] = *(uint4*)hu;
        *(uint4*)&Vtl[vd*VST + vk] = *(uint4*)lu;
    }
    __syncthreads();
    // ---- hoist fragments: K (A-side), Vt (B-side) ----
    short8 kfh[4], kfl[4];
    #pragma unroll
    for (int kt = 0; kt < 4; ++kt) {
        kfh[kt] = *(const short8*)&Kh[(kt*16 + l15)*KST + quad*8];
        kfl[kt] = *(const short8*)&Kl[(kt*16 + l15)*KST + quad*8];
    }
    short8 vfh[2][2], vfl[2][2];   // [chunk c][d-tile nt]
    #pragma unroll
    for (int c = 0; c < 2; ++c)
        #pragma unroll
        for (int nt = 0; nt < 2; ++nt) {
            vfh[c][nt] = *(const short8*)&Vth[(nt*16 + l15)*VST + c*32 + quad*8];
            vfl[c][nt] = *(const short8*)&Vtl[(nt*16 + l15)*VST + c*32 + quad*8];
        }
    __syncthreads();   // staging LDS now dead -> safe to alias with P
    ushort* Ph = (ushort*)(smem + wv*4608);       // 16*VST us
    ushort* Pl = Ph + 1152;

    // ---- pixel tiles ----
    #pragma unroll
    for (int pt = 0; pt < 4; ++pt) {
        int ph = wv*4 + pt;
        const float* qp = qbuf
            + ((((size_t)n*128 + wh*16 + ph)*128 + ww*16 + l15)*256)
            + head*32 + quad*8;
        float4 q0 = *(const float4*)qp;
        float4 q1 = *(const float4*)(qp + 4);
        float qv[8] = {q0.x,q0.y,q0.z,q0.w, q1.x,q1.y,q1.z,q1.w};
        ushort qh_[8], ql_[8];
        #pragma unroll
        for (int j = 0; j < 8; ++j) split1(qv[j]*SCALE_, qh_[j], ql_[j]);
        short8 qh = *(short8*)qh_, ql = *(short8*)ql_;
        f32x4 s[4];
        #pragma unroll
        for (int kt = 0; kt < 4; ++kt) s[kt] = f32x4{0.f,0.f,0.f,0.f};
        #pragma unroll
        for (int kt = 0; kt < 4; ++kt) {
            s[kt] = __builtin_amdgcn_mfma_f32_16x16x32_bf16(kfh[kt], qh, s[kt], 0, 0, 0);
            s[kt] = __builtin_amdgcn_mfma_f32_16x16x32_bf16(kfh[kt], ql, s[kt], 0, 0, 0);
            s[kt] = __builtin_amdgcn_mfma_f32_16x16x32_bf16(kfl[kt], qh, s[kt], 0, 0, 0);
        }
        float m = -3.0e38f;
        #pragma unroll
        for (int kt = 0; kt < 4; ++kt)
            #pragma unroll
            for (int r = 0; r < 4; ++r) m = fmaxf(m, s[kt][r]);
        m = fmaxf(m, __shfl_xor(m, 16));
        m = fmaxf(m, __shfl_xor(m, 32));
        float p[16]; float lsum = 0.f;
        #pragma unroll
        for (int kt = 0; kt < 4; ++kt)
            #pragma unroll
            for (int r = 0; r < 4; ++r) {
                float pe = __expf(s[kt][r] - m);
                p[kt*4 + r] = pe;
                lsum += pe;
            }
        lsum += __shfl_xor(lsum, 16);
        lsum += __shfl_xor(lsum, 32);
        float inv = 1.f / lsum;
        #pragma unroll
        for (int kt = 0; kt < 4; ++kt) {
            ushort h4[4], l4[4];
            #pragma unroll
            for (int r = 0; r < 4; ++r) split1(p[kt*4 + r]*inv, h4[r], l4[r]);
            uint2 wph = { (uint)h4[0] | ((uint)h4[1] << 16),
                          (uint)h4[2] | ((uint)h4[3] << 16) };
            uint2 wpl = { (uint)l4[0] | ((uint)l4[1] << 16),
                          (uint)l4[2] | ((uint)l4[3] << 16) };
            *(uint2*)&Ph[l15*VST + kt*16 + quad*4] = wph;
            *(uint2*)&Pl[l15*VST + kt*16 + quad*4] = wpl;
        }
        short8 pfh[2], pfl[2];
        #pragma unroll
        for (int c = 0; c < 2; ++c) {
            pfh[c] = *(const short8*)&Ph[l15*VST + c*32 + quad*8];
            pfl[c] = *(const short8*)&Pl[l15*VST + c*32 + quad*8];
        }
        f32x4 o[2];
        o[0] = f32x4{0.f,0.f,0.f,0.f};
        o[1] = f32x4{0.f,0.f,0.f,0.f};
        #pragma unroll
        for (int c = 0; c < 2; ++c)
            #pragma unroll
            for (int nt = 0; nt < 2; ++nt) {
                o[nt] = __builtin_amdgcn_mfma_f32_16x16x32_bf16(pfh[c], vfh[c][nt], o[nt], 0, 0, 0);
                o[nt] = __builtin_amdgcn_mfma_f32_16x16x32_bf16(pfl[c], vfh[c][nt], o[nt], 0, 0, 0);
                o[nt] = __builtin_amdgcn_mfma_f32_16x16x32_bf16(pfh[c], vfl[c][nt], o[nt], 0, 0, 0);
            }
        #pragma unroll
        for (int r = 0; r < 4; ++r) {
            float* orow = out
                + ((((size_t)n*128 + wh*16 + ph)*128 + ww*16 + quad*4 + r)*256)
                + head*32 + l15;
            #pragma unroll
            for (int nt = 0; nt < 2; ++nt)
                orow[nt*16] += o[nt][r];
        }
    }
}

extern "C" void kernel_launch(void* const* d_in, const int* in_sizes, int n_in,
                              void* d_out, int out_size, void* d_ws, size_t ws_size,
                              hipStream_t stream)
{
    const float* x1   = (const float*)d_in[0];
    const float* x2   = (const float*)d_in[1];
    const float* Wqkv = (const float*)d_in[2];
    const float* bqkv = (const float*)d_in[3];
    const float* lw   = (const float*)d_in[4];
    const float* lb   = (const float*)d_in[5];
    const float* Wo   = (const float*)d_in[6];
    const float* bo   = (const float*)d_in[7];
    float* out1 = (float*)d_out;
    float* out2 = out1 + (size_t)TOK_*C_;

    float* ws    = (float*)d_ws;
    float* xpool = ws;                          //  2,097,152 f
    float* xwm   = xpool + 2097152;             //    131,072 f
    float* kvp   = xwm   + 131072;              //  4,194,304 f
    float* qwin  = kvp   + 4194304;             //    131,072 f
    float* kwin  = qwin  + 131072;              //    131,072 f
    int*   idx   = (int*)(kwin + 131072);       //      2,048 i
    ushort* Wh   = (ushort*)(idx + 2048);       //    262,144 us
    ushort* Wl   = Wh + 262144;                 //    262,144 us
    float* bufQ1 = (float*)(Wl + 262144);       // 16,777,216 f
    float* bufQ2 = bufQ1 + 16777216;            // 16,777,216 f
    float* bufV1 = bufQ2 + 16777216;            // 16,777,216 f
    float* bufV2 = bufV1 + 16777216;            // 16,777,216 f

    // 0) pre-split weights (Wqkv rows 0-767, Wo rows 768-1023)
    wsplit_kernel<<<dim3(256), dim3(256), 0, stream>>>(Wqkv, Wo, Wh, Wl);
    // 1) pooled image + window means (both branches)
    pool_kernel<<<dim3(512), dim3(256), 0, stream>>>(x1, x2, xpool, xwm);
    // 2) kv_pool: k (cols 0-255) and v (cols 256-511) of kvp, pair-batched
    gemm_mfma<<<dim3(64,2), dim3(256), 0, stream>>>(
        xpool, xpool, Wh, Wl, 256, 512, bqkv+256, bqkv+512,
        kvp, kvp+256, 512, 512);
    // 3) window-mean projections q/k, pair-batched (M=512)
    gemm_mfma<<<dim3(4,2), dim3(256), 0, stream>>>(
        xwm, xwm, Wh, Wl, 0, 256, bqkv, bqkv+256,
        qwin, kwin, 256, 256);
    // 4) routing (both pairs)
    route_kernel<<<dim3(512), dim3(64), 0, stream>>>(qwin, kwin, idx);
    // 5) batch A: q2 (from x2) + v1 (from x1)
    gemm_mfma<<<dim3(512,2), dim3(256), 0, stream>>>(
        x2, x1, Wh, Wl, 0, 512, bqkv, bqkv+512,
        bufQ2, bufV1, 256, 256);
    // 6) batch B: q1 (from x1) + v2 (from x2)
    gemm_mfma<<<dim3(512,2), dim3(256), 0, stream>>>(
        x1, x2, Wh, Wl, 0, 512, bqkv, bqkv+512,
        bufQ1, bufV2, 256, 256);
    // 7) lepe -> out1/out2
    lepe_kernel<<<dim3(2048), dim3(256), 0, stream>>>(bufV1, lw, lb, out1);
    lepe_kernel<<<dim3(2048), dim3(256), 0, stream>>>(bufV2, lw, lb, out2);
    // 8) attention: attend(q2, kv1, idx1) += out1 ; attend(q1, kv2, idx2) += out2
    attn_kernel<<<dim3(256,8), dim3(256), 0, stream>>>(bufQ2, kvp, idx, out1);
    attn_kernel<<<dim3(256,8), dim3(256), 0, stream>>>(bufQ1, kvp + 2097152, idx + N_*64*4, out2);
    // 9) final projection, pair-batched, in-place (blocks own rows exclusively)
    gemm_mfma<<<dim3(512,2), dim3(256), 0, stream>>>(
        out1, out2, Wh, Wl, 768, 768, bo, bo,
        out1, out2, 256, 256);
}